// Round 3
// baseline (364.578 us; speedup 1.0000x reference)
//
#include <hip/hip_runtime.h>

#define T_STEPS 100
#define CHUNKS  25     // 100 floats = 25 float4 per element
#define TPB     256    // 4 independent waves per block, no barriers
#define GF4     5      // pipeline group: 5 float4 = 20 timesteps

// v4: LDS-FREE. v2/v3 post-mortems showed the LDS staging machinery (DMA
// drains, capacity wall at 400 B/element, per-slice syncs) is itself the
// bottleneck. Each thread instead loads its OWN contiguous 400 B row
// directly to VGPRs:
//  - per global_load_dwordx4 the wave touches 64 distinct lines (400 B
//    lane-stride), but every 16 B chunk is line-interior (16-aligned) and
//    the next 3 loads re-hit the same lines via L1 -> unique-line traffic
//    1.12x of ideal; the tax is L1-tag cycles (~26% capacity), not HBM bytes
//  - 3-group x 5-float4 register pipeline (depth-2 prefetch): while group g
//    is consumed, g+1 and g+2 are in flight; compiler inserts counted
//    waitcnts per group (hardware dep tracking on dest VGPRs)
//  - zero LDS, zero barriers -> occupancy VGPR-limited: ~90-110 VGPR
//    (launch_bounds cap 128) = 16 waves/CU, 2.7x the v1 LDS-capped 6
//  - output: verified v2/v3 path — 100 spike bits packed in 4 u32 during
//    the recurrence (exact: spike in {0,1}), ds_bpermute wave transpose
//    (LDS hardware, no LDS space), 25 coalesced float4 stores per wave
//
// NUMERICS: float ops identical to the bit-exact v1/v2/v3 (contract off;
//   ((mem*TAU)+x)-w ; (BETA*w)+0.1*((A*m)+(B*s)); mem - spike*THRESH).
__global__ __launch_bounds__(TPB, 4) void lif_kernel(const float* __restrict__ x,
                                                     float* __restrict__ out) {
#pragma clang fp contract(off)
    const int tid  = threadIdx.x;
    const int lane = tid & 63;
    const int w    = tid >> 6;

    // thread = element; wave handles 64 consecutive elements
    const size_t e = (size_t)blockIdx.x * TPB + (size_t)tid;
    const float4* __restrict__ xr = (const float4*)x + e * CHUNKS;

    unsigned b0 = 0, b1 = 0, b2 = 0, b3 = 0;
    float mem = 0.0f, wreg = 0.0f;

#define LOADG(G, g)                                                   \
    do {                                                              \
        _Pragma("unroll")                                             \
        for (int i = 0; i < GF4; ++i) G[i] = xr[(g) * GF4 + i];       \
    } while (0)

#define CONSUME(G, s)                                                       \
    do {                                                                    \
        _Pragma("unroll")                                                   \
        for (int c = 0; c < GF4; ++c) {                                     \
            float xs[4] = {G[c].x, G[c].y, G[c].z, G[c].w};                 \
            _Pragma("unroll")                                               \
            for (int j = 0; j < 4; ++j) {                                   \
                mem = (mem * 0.5f + xs[j]) - wreg;     /* ((mem*TAU)+x)-w */\
                const bool fire = (mem - 0.5f) > 0.0f; /* ZIF forward */    \
                const float spike = fire ? 1.0f : 0.0f;                     \
                wreg = 0.9f * wreg + 0.1f * (0.5f * mem + 0.5f * spike);    \
                mem = mem - spike * 0.5f;              /* soft reset */     \
                const int t = (s) * 20 + c * 4 + j;    /* compile-time */   \
                const unsigned bit = fire ? 1u : 0u;                        \
                if (t < 32)      b0 |= bit << t;                            \
                else if (t < 64) b1 |= bit << (t - 32);                     \
                else if (t < 96) b2 |= bit << (t - 64);                     \
                else             b3 |= bit << (t - 96);                     \
            }                                                               \
        }                                                                   \
    } while (0)

    // ---- 3-buffer register pipeline over 5 groups (depth-2 prefetch) ----
    float4 GA[GF4], GB[GF4], GC[GF4];
    LOADG(GA, 0);
    LOADG(GB, 1);
    LOADG(GC, 2);

    CONSUME(GA, 0);
    LOADG(GA, 3);           // in flight under groups 1-2's compute
    CONSUME(GB, 1);
    LOADG(GB, 4);           // in flight under groups 2-3's compute
    CONSUME(GC, 2);
    CONSUME(GA, 3);
    CONSUME(GB, 4);

#undef LOADG
#undef CONSUME

    // ---- stage-out: bpermute elem bits -> coalesced float4 stores (per wave)
    float4* __restrict__ ow =
        (float4*)out + ((size_t)blockIdx.x * TPB + (size_t)w * 64) * CHUNKS;
#pragma unroll
    for (int k = 0; k < CHUNKS; ++k) {
        const int f = k * 64 + lane;        // wave-local output float4 index
        const int el = f / 25;              // source element (lane) within wave
        const int c  = f - el * 25;         // chunk within element
        const int a  = el << 2;             // bpermute byte address
        const unsigned w0 = (unsigned)__builtin_amdgcn_ds_bpermute(a, (int)b0);
        const unsigned w1 = (unsigned)__builtin_amdgcn_ds_bpermute(a, (int)b1);
        const unsigned w2 = (unsigned)__builtin_amdgcn_ds_bpermute(a, (int)b2);
        const unsigned w3 = (unsigned)__builtin_amdgcn_ds_bpermute(a, (int)b3);
        const unsigned word = (c < 16) ? ((c < 8) ? w0 : w1)
                                       : ((c < 24) ? w2 : w3);
        const int sh = (c & 7) * 4;         // bits 4c..4c+3 of element el
        float4 sv;
        sv.x = ((word >> (sh + 0)) & 1u) ? 1.0f : 0.0f;
        sv.y = ((word >> (sh + 1)) & 1u) ? 1.0f : 0.0f;
        sv.z = ((word >> (sh + 2)) & 1u) ? 1.0f : 0.0f;
        sv.w = ((word >> (sh + 3)) & 1u) ? 1.0f : 0.0f;
        ow[f] = sv;
    }
}

extern "C" void kernel_launch(void* const* d_in, const int* in_sizes, int n_in,
                              void* d_out, int out_size, void* d_ws, size_t ws_size,
                              hipStream_t stream) {
    const float* x = (const float*)d_in[0];
    float* out = (float*)d_out;
    int n_elem = in_sizes[0] / T_STEPS;   // 64*8192 = 524288
    int grid = n_elem / TPB;              // 2048 blocks, exact

    lif_kernel<<<grid, TPB, 0, stream>>>(x, out);
}